// Round 1
// baseline (709.878 us; speedup 1.0000x reference)
//
#include <hip/hip_runtime.h>
#include <hip/hip_bf16.h>

using f32x4  = float          __attribute__((ext_vector_type(4)));
using bf16x8 = __bf16         __attribute__((ext_vector_type(8)));
using u16x8  = unsigned short __attribute__((ext_vector_type(8)));

#define C_CH 512
#define H_IN 37
#define W_IN 50
#define NPOS 1850       // 37*50
#define NROI 512
#define DIN  25088      // 512*49
#define DFC  4096
#define NPAR 84
#define NCLS 21

__device__ __forceinline__ unsigned pack_bf16x2(float a, float b) {
    __hip_bfloat162 h;
    h.x = __float2bfloat16(a);
    h.y = __float2bfloat16(b);
    return *reinterpret_cast<unsigned*>(&h);
}

// ---------------------------------------------------------------------------
// x (512, 37, 50) fp32  ->  xt (1850, 512) fp32   (channels innermost)
// ---------------------------------------------------------------------------
__global__ __launch_bounds__(256) void transpose_x_kernel(
        const float* __restrict__ x, float* __restrict__ xt) {
    __shared__ float tile[64][65];
    int p0 = blockIdx.x * 64;           // position tile
    int c0 = blockIdx.y * 64;           // channel tile
    int t  = threadIdx.x;
    int tc = t & 63, tr = t >> 6;
#pragma unroll
    for (int i = 0; i < 16; ++i) {
        int r = tr + i * 4;             // channel offset in tile
        int p = p0 + tc;
        float v = 0.f;
        if (p < NPOS) v = x[(size_t)(c0 + r) * NPOS + p];
        tile[r][tc] = v;
    }
    __syncthreads();
#pragma unroll
    for (int i = 0; i < 16; ++i) {
        int rw = tr + i * 4;            // position offset in tile
        int p = p0 + rw;
        if (p < NPOS) xt[(size_t)p * C_CH + c0 + tc] = tile[tc][rw];
    }
}

// ---------------------------------------------------------------------------
// W (K, 4096) fp32 -> WT (4096, Ktot) bf16.  perm=1 applies the RoI-k
// permutation: dest col k' = bin*512 + ch  maps from source row ch*49 + bin.
// ---------------------------------------------------------------------------
__global__ __launch_bounds__(256) void transpose_w_kernel(
        const float* __restrict__ W, __hip_bfloat16* __restrict__ WT,
        int Ktot, int perm) {
    __shared__ float tile[64][65];
    int f0 = blockIdx.x * 64;           // dest row (N) tile
    int k0 = blockIdx.y * 64;           // dest col (K') tile
    int t  = threadIdx.x;
    int tc = t & 63, tr = t >> 6;
#pragma unroll
    for (int i = 0; i < 16; ++i) {
        int r  = tr + i * 4;            // k' offset
        int kp = k0 + r;
        int srow = perm ? ((kp & 511) * 49 + (kp >> 9)) : kp;
        tile[r][tc] = W[(size_t)srow * DFC + f0 + tc];
    }
    __syncthreads();
    int pairc = (t & 31) * 2;           // k' pair within tile
    int rw0   = t >> 5;                 // f within tile (0..7)
#pragma unroll
    for (int i = 0; i < 8; ++i) {
        int rw = rw0 + i * 8;
        unsigned pk = pack_bf16x2(tile[pairc][rw], tile[pairc + 1][rw]);
        *reinterpret_cast<unsigned*>(WT + (size_t)(f0 + rw) * Ktot + k0 + pairc) = pk;
    }
}

// ---------------------------------------------------------------------------
// RoI max-pool.  One block (256 thr) per ROI; thread t owns channels 2t,2t+1.
// pooled layout: [n][bin*512 + ch] bf16 (K-permuted to match W1T).
// ---------------------------------------------------------------------------
__global__ __launch_bounds__(256) void roi_pool_kernel(
        const float* __restrict__ xt, const float* __restrict__ rois,
        __hip_bfloat16* __restrict__ pooled) {
    int n = blockIdx.x;
    int t = threadIdx.x;
    float4 rv = reinterpret_cast<const float4*>(rois)[n];
    int x1 = (int)fminf(fmaxf(rintf(rv.x * 0.0625f), 0.f), (float)W_IN);
    int y1 = (int)fminf(fmaxf(rintf(rv.y * 0.0625f), 0.f), (float)H_IN);
    int x2 = (int)fminf(fmaxf(rintf(rv.z * 0.0625f), 0.f), (float)W_IN);
    int y2 = (int)fminf(fmaxf(rintf(rv.w * 0.0625f), 0.f), (float)H_IN);
    bool valid = (x1 < x2) && (y1 < y2);
    unsigned* outp = reinterpret_cast<unsigned*>(pooled) + (size_t)n * (DIN / 2);
    if (!valid) {
        for (int b = 0; b < 49; ++b) outp[b * 256 + t] = 0u;
        return;
    }
    int x2e = min(x2, W_IN - 1), y2e = min(y2, H_IN - 1);
    int Hc = y2e - y1 + 1, Wc = x2e - x1 + 1;
    const float2* base = reinterpret_cast<const float2*>(xt);
    for (int i = 0; i < 7; ++i) {
        int rs = y1 + (i * Hc) / 7;
        int re = y1 + ((i + 1) * Hc + 6) / 7;
        for (int j = 0; j < 7; ++j) {
            int cs = x1 + (j * Wc) / 7;
            int ce = x1 + ((j + 1) * Wc + 6) / 7;
            float m0 = -__builtin_inff(), m1 = -__builtin_inff();
            for (int r = rs; r < re; ++r) {
                const float2* rowp = base + (size_t)r * (W_IN * C_CH / 2) + t;
                for (int c = cs; c < ce; ++c) {
                    float2 v = rowp[c * (C_CH / 2)];
                    m0 = fmaxf(m0, v.x);
                    m1 = fmaxf(m1, v.y);
                }
            }
            outp[(i * 7 + j) * 256 + t] = pack_bf16x2(m0, m1);
        }
    }
}

// ---------------------------------------------------------------------------
// bf16 GEMM, m97 structure: 128x128 tile, BK=64, 4 waves (2x2), 16x16x32 MFMA,
// global_load_lds width 16, XOR-swizzled LDS, split-K partials (fp32).
// A: [M][lda] bf16 row-major; Bt: [N][ldb] bf16 (B transposed, K contiguous).
// Cp: [KS][Mtot][N] fp32.
// ---------------------------------------------------------------------------
__device__ __forceinline__ void gload_lds16(const void* src, void* dst) {
    __builtin_amdgcn_global_load_lds(
        (const __attribute__((address_space(1))) void*)src,
        (__attribute__((address_space(3))) void*)dst, 16, 0, 0);
}

__global__ __launch_bounds__(256, 2) void gemm_bf16_kernel(
        const __hip_bfloat16* __restrict__ A,
        const __hip_bfloat16* __restrict__ Bt,
        float* __restrict__ Cp,
        int N, int lda, int ldb, int kChunk, int nMT, int nNT, int Mtot) {
    __shared__ __align__(16) char lA[128 * 128];
    __shared__ __align__(16) char lB[128 * 128];
    int bid = blockIdx.x;
    int mt = bid % nMT;
    int nt = (bid / nMT) % nNT;
    int ks = bid / (nMT * nNT);
    int m0 = mt * 128, n0 = nt * 128;
    size_t k0 = (size_t)ks * kChunk;
    int t = threadIdx.x;
    int lane = t & 63, wid = t >> 6;

    const char* srcA[4]; const char* srcB[4];
    char* dstA[4]; char* dstB[4];
#pragma unroll
    for (int i = 0; i < 4; ++i) {
        int chunk = i * 4 + wid;                  // 1KB LDS chunk per wave-issue
        int p = chunk * 1024 + lane * 16;         // physical LDS byte
        int row = p >> 7;                         // 128B per row (64 bf16)
        int kb = (p & 127) ^ ((row & 7) << 4);    // inverse-swizzled source col
        srcA[i] = (const char*)A  + ((size_t)(m0 + row) * lda + k0) * 2 + kb;
        srcB[i] = (const char*)Bt + ((size_t)(n0 + row) * ldb + k0) * 2 + kb;
        dstA[i] = lA + chunk * 1024;
        dstB[i] = lB + chunk * 1024;
    }

    int wm = wid >> 1, wn = wid & 1;
    int swz = (lane & 7) << 4;
    int kb0 = (lane >> 4) << 4;                   // k-fragment byte offset
    int roA[4], roB[4];
#pragma unroll
    for (int f = 0; f < 4; ++f) {
        roA[f] = (wm * 64 + f * 16 + (lane & 15)) * 128;
        roB[f] = (wn * 64 + f * 16 + (lane & 15)) * 128;
    }

    f32x4 acc[4][4] = {};
    for (int kt = 0; kt < kChunk; kt += 64) {
#pragma unroll
        for (int i = 0; i < 4; ++i) gload_lds16(srcA[i], dstA[i]);
#pragma unroll
        for (int i = 0; i < 4; ++i) gload_lds16(srcB[i], dstB[i]);
#pragma unroll
        for (int i = 0; i < 4; ++i) { srcA[i] += 128; srcB[i] += 128; }
        __syncthreads();
#pragma unroll
        for (int ksub = 0; ksub < 2; ++ksub) {
            int kk = (kb0 | (ksub << 6)) ^ swz;
            bf16x8 af[4], bfr[4];
#pragma unroll
            for (int f = 0; f < 4; ++f)
                af[f] = *reinterpret_cast<const bf16x8*>(lA + roA[f] + kk);
#pragma unroll
            for (int f = 0; f < 4; ++f)
                bfr[f] = *reinterpret_cast<const bf16x8*>(lB + roB[f] + kk);
#pragma unroll
            for (int mf = 0; mf < 4; ++mf)
#pragma unroll
                for (int nf = 0; nf < 4; ++nf)
                    acc[mf][nf] = __builtin_amdgcn_mfma_f32_16x16x32_bf16(
                        af[mf], bfr[nf], acc[mf][nf], 0, 0, 0);
        }
        __syncthreads();
    }

    float* outp = Cp + (size_t)ks * Mtot * N;
    int rbase = m0 + wm * 64;
    int cbase = n0 + wn * 64 + (lane & 15);
    int rl = (lane >> 4) * 4;
#pragma unroll
    for (int mf = 0; mf < 4; ++mf)
#pragma unroll
        for (int nf = 0; nf < 4; ++nf)
#pragma unroll
            for (int r = 0; r < 4; ++r)
                outp[(size_t)(rbase + mf * 16 + rl + r) * N + cbase + nf * 16] =
                    acc[mf][nf][r];
}

// ---------------------------------------------------------------------------
// Sum KS split-K partials + bias, ReLU, convert to bf16.
// ---------------------------------------------------------------------------
__global__ __launch_bounds__(256) void reduce_bias_relu_kernel(
        const float* __restrict__ P, const float* __restrict__ bias,
        __hip_bfloat16* __restrict__ out, int MN, int N) {
    int idx = blockIdx.x * blockDim.x + threadIdx.x;
    int e0 = idx * 4;
    if (e0 >= MN) return;
    f32x4 s = *reinterpret_cast<const f32x4*>(P + e0);
#pragma unroll
    for (int k = 1; k < 4; ++k)
        s += *reinterpret_cast<const f32x4*>(P + (size_t)k * MN + e0);
    f32x4 b = *reinterpret_cast<const f32x4*>(bias + (e0 & (N - 1)));
    s += b;
    uint2 pk;
    pk.x = pack_bf16x2(fmaxf(s[0], 0.f), fmaxf(s[1], 0.f));
    pk.y = pack_bf16x2(fmaxf(s[2], 0.f), fmaxf(s[3], 0.f));
    *reinterpret_cast<uint2*>(reinterpret_cast<char*>(out) + (size_t)e0 * 2) = pk;
}

// ---------------------------------------------------------------------------
// Head: params = fc7 @ Wp + bp ; scores = fc7 @ Ws + bs.  Block per ROI.
// ---------------------------------------------------------------------------
__global__ __launch_bounds__(128) void head_kernel(
        const __hip_bfloat16* __restrict__ fc7,
        const float* __restrict__ Wp, const float* __restrict__ bp,
        const float* __restrict__ Ws, const float* __restrict__ bs,
        float* __restrict__ out) {
    __shared__ float rowf[DFC];
    int n = blockIdx.x;
    int t = threadIdx.x;
#pragma unroll
    for (int i = 0; i < 4; ++i) {
        int base = (t + i * 128) * 8;
        u16x8 v = *reinterpret_cast<const u16x8*>(fc7 + (size_t)n * DFC + base);
#pragma unroll
        for (int j = 0; j < 8; ++j)
            rowf[base + j] = __uint_as_float(((unsigned)v[j]) << 16);
    }
    __syncthreads();
    if (t < NPAR + NCLS) {
        bool isp = t < NPAR;
        const float* W = isp ? (Wp + t) : (Ws + (t - NPAR));
        int stride = isp ? NPAR : NCLS;
        float acc = 0.f;
#pragma unroll 8
        for (int k = 0; k < DFC; ++k)
            acc = fmaf(rowf[k], W[(size_t)k * stride], acc);
        if (isp) out[(size_t)n * NPAR + t] = acc + bp[t];
        else     out[(size_t)NROI * NPAR + (size_t)n * NCLS + (t - NPAR)] = acc + bs[t - NPAR];
    }
}

// ---------------------------------------------------------------------------
extern "C" void kernel_launch(void* const* d_in, const int* in_sizes, int n_in,
                              void* d_out, int out_size, void* d_ws, size_t ws_size,
                              hipStream_t stream) {
    const float* x    = (const float*)d_in[0];
    const float* rois = (const float*)d_in[1];
    // d_in[2] roi_index: B=1 -> always 0, unused
    const float* W1 = (const float*)d_in[3];
    const float* b1 = (const float*)d_in[4];
    const float* W2 = (const float*)d_in[5];
    const float* b2 = (const float*)d_in[6];
    const float* Wp = (const float*)d_in[7];
    const float* bp = (const float*)d_in[8];
    const float* Ws = (const float*)d_in[9];
    const float* bs = (const float*)d_in[10];
    float* out = (float*)d_out;

    const size_t MB = 1ull << 20;
    char* ws = (char*)d_ws;
    float*          xt     = (float*)(ws + 0);             // 3,788,800 B
    __hip_bfloat16* pooled = (__hip_bfloat16*)(ws + 4   * MB);  // 25.7 MB
    __hip_bfloat16* W1T    = (__hip_bfloat16*)(ws + 32  * MB);  // 196 MB
    __hip_bfloat16* W2T    = (__hip_bfloat16*)(ws + 240 * MB);  // 32 MB
    float*          part   = (float*)(ws + 274 * MB);           // 32 MB
    __hip_bfloat16* fc6    = (__hip_bfloat16*)(ws + 308 * MB);  // 4 MB
    __hip_bfloat16* fc7    = (__hip_bfloat16*)(ws + 313 * MB);  // 4 MB

    transpose_x_kernel<<<dim3(29, 8), 256, 0, stream>>>(x, xt);
    transpose_w_kernel<<<dim3(64, 392), 256, 0, stream>>>(W1, W1T, DIN, 1);
    transpose_w_kernel<<<dim3(64, 64),  256, 0, stream>>>(W2, W2T, DFC, 0);
    roi_pool_kernel<<<NROI, 256, 0, stream>>>(xt, rois, pooled);

    // fc6 = relu(pooled @ W1 + b1):  M=512 N=4096 K=25088, split-K=4
    gemm_bf16_kernel<<<512, 256, 0, stream>>>(pooled, W1T, part,
                                              DFC, DIN, DIN, DIN / 4, 4, 32, NROI);
    reduce_bias_relu_kernel<<<2048, 256, 0, stream>>>(part, b1, fc6, NROI * DFC, DFC);

    // fc7 = relu(fc6 @ W2 + b2):  M=512 N=4096 K=4096, split-K=4
    gemm_bf16_kernel<<<512, 256, 0, stream>>>(fc6, W2T, part,
                                              DFC, DFC, DFC, DFC / 4, 4, 32, NROI);
    reduce_bias_relu_kernel<<<2048, 256, 0, stream>>>(part, b2, fc7, NROI * DFC, DFC);

    head_kernel<<<NROI, 128, 0, stream>>>(fc7, Wp, bp, Ws, bs, out);
}

// Round 2
// 484.330 us; speedup vs baseline: 1.4657x; 1.4657x over previous
//
#include <hip/hip_runtime.h>
#include <hip/hip_bf16.h>

using f32x4  = float          __attribute__((ext_vector_type(4)));
using bf16x8 = __bf16         __attribute__((ext_vector_type(8)));
using u16x8  = unsigned short __attribute__((ext_vector_type(8)));

#define C_CH 512
#define H_IN 37
#define W_IN 50
#define NPOS 1850       // 37*50
#define NROI 512
#define DIN  25088      // 512*49
#define DFC  4096
#define NPAR 84
#define NCLS 21
#define KS_HEAD 16

__device__ __forceinline__ unsigned pack_bf16x2(float a, float b) {
    __hip_bfloat162 h;
    h.x = __float2bfloat16(a);
    h.y = __float2bfloat16(b);
    return *reinterpret_cast<unsigned*>(&h);
}

// ---------------------------------------------------------------------------
// x (512, 37, 50) fp32  ->  xt (1850, 512) fp32   (channels innermost)
// ---------------------------------------------------------------------------
__global__ __launch_bounds__(256) void transpose_x_kernel(
        const float* __restrict__ x, float* __restrict__ xt) {
    __shared__ float tile[64][65];
    int p0 = blockIdx.x * 64;           // position tile
    int c0 = blockIdx.y * 64;           // channel tile
    int t  = threadIdx.x;
    int tc = t & 63, tr = t >> 6;
#pragma unroll
    for (int i = 0; i < 16; ++i) {
        int r = tr + i * 4;             // channel offset in tile
        int p = p0 + tc;
        float v = 0.f;
        if (p < NPOS) v = x[(size_t)(c0 + r) * NPOS + p];
        tile[r][tc] = v;
    }
    __syncthreads();
#pragma unroll
    for (int i = 0; i < 16; ++i) {
        int rw = tr + i * 4;            // position offset in tile
        int p = p0 + rw;
        if (p < NPOS) xt[(size_t)p * C_CH + c0 + tc] = tile[tc][rw];
    }
}

// ---------------------------------------------------------------------------
// W (K, 4096) fp32 -> WT (4096, Ktot) bf16.  perm=1 applies the RoI-k
// permutation: dest col k' = bin*512 + ch  maps from source row ch*49 + bin.
// ---------------------------------------------------------------------------
__global__ __launch_bounds__(256) void transpose_w_kernel(
        const float* __restrict__ W, __hip_bfloat16* __restrict__ WT,
        int Ktot, int perm) {
    __shared__ float tile[64][65];
    int f0 = blockIdx.x * 64;           // dest row (N) tile
    int k0 = blockIdx.y * 64;           // dest col (K') tile
    int t  = threadIdx.x;
    int tc = t & 63, tr = t >> 6;
#pragma unroll
    for (int i = 0; i < 16; ++i) {
        int r  = tr + i * 4;            // k' offset
        int kp = k0 + r;
        int srow = perm ? ((kp & 511) * 49 + (kp >> 9)) : kp;
        tile[r][tc] = W[(size_t)srow * DFC + f0 + tc];
    }
    __syncthreads();
    int pairc = (t & 31) * 2;           // k' pair within tile
    int rw0   = t >> 5;                 // f within tile (0..7)
#pragma unroll
    for (int i = 0; i < 8; ++i) {
        int rw = rw0 + i * 8;
        unsigned pk = pack_bf16x2(tile[pairc][rw], tile[pairc + 1][rw]);
        *reinterpret_cast<unsigned*>(WT + (size_t)(f0 + rw) * Ktot + k0 + pairc) = pk;
    }
}

// ---------------------------------------------------------------------------
// RoI max-pool.  One block (256 thr) per ROI; thread t owns channels 2t,2t+1.
// pooled layout: [n][bin*512 + ch] bf16 (K-permuted to match W1T).
// ---------------------------------------------------------------------------
__global__ __launch_bounds__(256) void roi_pool_kernel(
        const float* __restrict__ xt, const float* __restrict__ rois,
        __hip_bfloat16* __restrict__ pooled) {
    int n = blockIdx.x;
    int t = threadIdx.x;
    float4 rv = reinterpret_cast<const float4*>(rois)[n];
    int x1 = (int)fminf(fmaxf(rintf(rv.x * 0.0625f), 0.f), (float)W_IN);
    int y1 = (int)fminf(fmaxf(rintf(rv.y * 0.0625f), 0.f), (float)H_IN);
    int x2 = (int)fminf(fmaxf(rintf(rv.z * 0.0625f), 0.f), (float)W_IN);
    int y2 = (int)fminf(fmaxf(rintf(rv.w * 0.0625f), 0.f), (float)H_IN);
    bool valid = (x1 < x2) && (y1 < y2);
    unsigned* outp = reinterpret_cast<unsigned*>(pooled) + (size_t)n * (DIN / 2);
    if (!valid) {
        for (int b = 0; b < 49; ++b) outp[b * 256 + t] = 0u;
        return;
    }
    int x2e = min(x2, W_IN - 1), y2e = min(y2, H_IN - 1);
    int Hc = y2e - y1 + 1, Wc = x2e - x1 + 1;
    const float2* base = reinterpret_cast<const float2*>(xt);
    for (int i = 0; i < 7; ++i) {
        int rs = y1 + (i * Hc) / 7;
        int re = y1 + ((i + 1) * Hc + 6) / 7;
        for (int j = 0; j < 7; ++j) {
            int cs = x1 + (j * Wc) / 7;
            int ce = x1 + ((j + 1) * Wc + 6) / 7;
            float m0 = -__builtin_inff(), m1 = -__builtin_inff();
            for (int r = rs; r < re; ++r) {
                const float2* rowp = base + (size_t)r * (W_IN * C_CH / 2) + t;
                for (int c = cs; c < ce; ++c) {
                    float2 v = rowp[c * (C_CH / 2)];
                    m0 = fmaxf(m0, v.x);
                    m1 = fmaxf(m1, v.y);
                }
            }
            outp[(i * 7 + j) * 256 + t] = pack_bf16x2(m0, m1);
        }
    }
}

// ---------------------------------------------------------------------------
// bf16 GEMM, m97 structure: 128x128 tile, BK=64, 4 waves (2x2), 16x16x32 MFMA,
// global_load_lds width 16, XOR-swizzled LDS, split-K partials (fp32).
// A: [M][lda] bf16 row-major; Bt: [N][ldb] bf16 (B transposed, K contiguous).
// Cp: [KS][Mtot][N] fp32.
// ---------------------------------------------------------------------------
__device__ __forceinline__ void gload_lds16(const void* src, void* dst) {
    __builtin_amdgcn_global_load_lds(
        (const __attribute__((address_space(1))) void*)src,
        (__attribute__((address_space(3))) void*)dst, 16, 0, 0);
}

__global__ __launch_bounds__(256, 2) void gemm_bf16_kernel(
        const __hip_bfloat16* __restrict__ A,
        const __hip_bfloat16* __restrict__ Bt,
        float* __restrict__ Cp,
        int N, int lda, int ldb, int kChunk, int nMT, int nNT, int Mtot) {
    __shared__ __align__(16) char lA[128 * 128];
    __shared__ __align__(16) char lB[128 * 128];
    int bid = blockIdx.x;
    int mt = bid % nMT;
    int nt = (bid / nMT) % nNT;
    int ks = bid / (nMT * nNT);
    int m0 = mt * 128, n0 = nt * 128;
    size_t k0 = (size_t)ks * kChunk;
    int t = threadIdx.x;
    int lane = t & 63, wid = t >> 6;

    const char* srcA[4]; const char* srcB[4];
    char* dstA[4]; char* dstB[4];
#pragma unroll
    for (int i = 0; i < 4; ++i) {
        int chunk = i * 4 + wid;                  // 1KB LDS chunk per wave-issue
        int p = chunk * 1024 + lane * 16;         // physical LDS byte
        int row = p >> 7;                         // 128B per row (64 bf16)
        int kb = (p & 127) ^ ((row & 7) << 4);    // inverse-swizzled source col
        srcA[i] = (const char*)A  + ((size_t)(m0 + row) * lda + k0) * 2 + kb;
        srcB[i] = (const char*)Bt + ((size_t)(n0 + row) * ldb + k0) * 2 + kb;
        dstA[i] = lA + chunk * 1024;
        dstB[i] = lB + chunk * 1024;
    }

    int wm = wid >> 1, wn = wid & 1;
    int swz = (lane & 7) << 4;
    int kb0 = (lane >> 4) << 4;                   // k-fragment byte offset
    int roA[4], roB[4];
#pragma unroll
    for (int f = 0; f < 4; ++f) {
        roA[f] = (wm * 64 + f * 16 + (lane & 15)) * 128;
        roB[f] = (wn * 64 + f * 16 + (lane & 15)) * 128;
    }

    f32x4 acc[4][4] = {};
    for (int kt = 0; kt < kChunk; kt += 64) {
#pragma unroll
        for (int i = 0; i < 4; ++i) gload_lds16(srcA[i], dstA[i]);
#pragma unroll
        for (int i = 0; i < 4; ++i) gload_lds16(srcB[i], dstB[i]);
#pragma unroll
        for (int i = 0; i < 4; ++i) { srcA[i] += 128; srcB[i] += 128; }
        __syncthreads();
#pragma unroll
        for (int ksub = 0; ksub < 2; ++ksub) {
            int kk = (kb0 | (ksub << 6)) ^ swz;
            bf16x8 af[4], bfr[4];
#pragma unroll
            for (int f = 0; f < 4; ++f)
                af[f] = *reinterpret_cast<const bf16x8*>(lA + roA[f] + kk);
#pragma unroll
            for (int f = 0; f < 4; ++f)
                bfr[f] = *reinterpret_cast<const bf16x8*>(lB + roB[f] + kk);
#pragma unroll
            for (int mf = 0; mf < 4; ++mf)
#pragma unroll
                for (int nf = 0; nf < 4; ++nf)
                    acc[mf][nf] = __builtin_amdgcn_mfma_f32_16x16x32_bf16(
                        af[mf], bfr[nf], acc[mf][nf], 0, 0, 0);
        }
        __syncthreads();
    }

    float* outp = Cp + (size_t)ks * Mtot * N;
    int rbase = m0 + wm * 64;
    int cbase = n0 + wn * 64 + (lane & 15);
    int rl = (lane >> 4) * 4;
#pragma unroll
    for (int mf = 0; mf < 4; ++mf)
#pragma unroll
        for (int nf = 0; nf < 4; ++nf)
#pragma unroll
            for (int r = 0; r < 4; ++r)
                outp[(size_t)(rbase + mf * 16 + rl + r) * N + cbase + nf * 16] =
                    acc[mf][nf][r];
}

// ---------------------------------------------------------------------------
// Sum KS=4 split-K partials + bias, ReLU, convert to bf16.
// ---------------------------------------------------------------------------
__global__ __launch_bounds__(256) void reduce_bias_relu_kernel(
        const float* __restrict__ P, const float* __restrict__ bias,
        __hip_bfloat16* __restrict__ out, int MN, int N) {
    int idx = blockIdx.x * blockDim.x + threadIdx.x;
    int e0 = idx * 4;
    if (e0 >= MN) return;
    f32x4 s = *reinterpret_cast<const f32x4*>(P + e0);
#pragma unroll
    for (int k = 1; k < 4; ++k)
        s += *reinterpret_cast<const f32x4*>(P + (size_t)k * MN + e0);
    f32x4 b = *reinterpret_cast<const f32x4*>(bias + (e0 & (N - 1)));
    s += b;
    uint2 pk;
    pk.x = pack_bf16x2(fmaxf(s[0], 0.f), fmaxf(s[1], 0.f));
    pk.y = pack_bf16x2(fmaxf(s[2], 0.f), fmaxf(s[3], 0.f));
    *reinterpret_cast<uint2*>(reinterpret_cast<char*>(out) + (size_t)e0 * 2) = pk;
}

// ---------------------------------------------------------------------------
// Pack Wp (4096,84) || Ws (4096,21) -> WhT[128][4096] bf16 (B^T, zero-padded).
// ---------------------------------------------------------------------------
__global__ __launch_bounds__(256) void fill_whead_kernel(
        const float* __restrict__ Wp, const float* __restrict__ Ws,
        __hip_bfloat16* __restrict__ WhT) {
    int idx = blockIdx.x * 256 + threadIdx.x;     // over 128*4096
    int c = idx >> 12, k = idx & 4095;
    float v = 0.f;
    if (c < NPAR) v = Wp[(size_t)k * NPAR + c];
    else if (c < NPAR + NCLS) v = Ws[(size_t)k * NCLS + (c - NPAR)];
    WhT[idx] = __float2bfloat16(v);
}

// ---------------------------------------------------------------------------
// Sum KS_HEAD head partials + bias, scatter to (params, scores) output layout.
// P: [KS_HEAD][NROI][128] fp32.
// ---------------------------------------------------------------------------
__global__ __launch_bounds__(128) void head_reduce_kernel(
        const float* __restrict__ P, const float* __restrict__ bp,
        const float* __restrict__ bs, float* __restrict__ out) {
    int n = blockIdx.x, c = threadIdx.x;
    float s = 0.f;
#pragma unroll
    for (int ks = 0; ks < KS_HEAD; ++ks)
        s += P[(size_t)ks * NROI * 128 + (size_t)n * 128 + c];
    if (c < NPAR)
        out[(size_t)n * NPAR + c] = s + bp[c];
    else if (c < NPAR + NCLS)
        out[(size_t)NROI * NPAR + (size_t)n * NCLS + (c - NPAR)] = s + bs[c - NPAR];
}

// ---------------------------------------------------------------------------
extern "C" void kernel_launch(void* const* d_in, const int* in_sizes, int n_in,
                              void* d_out, int out_size, void* d_ws, size_t ws_size,
                              hipStream_t stream) {
    const float* x    = (const float*)d_in[0];
    const float* rois = (const float*)d_in[1];
    // d_in[2] roi_index: B=1 -> always 0, unused
    const float* W1 = (const float*)d_in[3];
    const float* b1 = (const float*)d_in[4];
    const float* W2 = (const float*)d_in[5];
    const float* b2 = (const float*)d_in[6];
    const float* Wp = (const float*)d_in[7];
    const float* bp = (const float*)d_in[8];
    const float* Ws = (const float*)d_in[9];
    const float* bs = (const float*)d_in[10];
    float* out = (float*)d_out;

    const size_t MB = 1ull << 20;
    char* ws = (char*)d_ws;
    float*          xt     = (float*)(ws + 0);                  // 3.62 MB
    __hip_bfloat16* pooled = (__hip_bfloat16*)(ws + 4   * MB);  // 24.5 MB
    __hip_bfloat16* WhT    = (__hip_bfloat16*)(ws + 30  * MB);  // 1 MB
    __hip_bfloat16* W1T    = (__hip_bfloat16*)(ws + 32  * MB);  // 196 MB
    __hip_bfloat16* W2T    = (__hip_bfloat16*)(ws + 240 * MB);  // 32 MB
    float*          part   = (float*)(ws + 274 * MB);           // 33.6 MB
    __hip_bfloat16* fc6    = (__hip_bfloat16*)(ws + 308 * MB);  // 4 MB
    __hip_bfloat16* fc7    = (__hip_bfloat16*)(ws + 313 * MB);  // 4 MB

    transpose_x_kernel<<<dim3(29, 8), 256, 0, stream>>>(x, xt);
    transpose_w_kernel<<<dim3(64, 392), 256, 0, stream>>>(W1, W1T, DIN, 1);
    transpose_w_kernel<<<dim3(64, 64),  256, 0, stream>>>(W2, W2T, DFC, 0);
    fill_whead_kernel<<<2048, 256, 0, stream>>>(Wp, Ws, WhT);
    roi_pool_kernel<<<NROI, 256, 0, stream>>>(xt, rois, pooled);

    // fc6 = relu(pooled @ W1 + b1):  M=512 N=4096 K=25088, split-K=4
    gemm_bf16_kernel<<<512, 256, 0, stream>>>(pooled, W1T, part,
                                              DFC, DIN, DIN, DIN / 4, 4, 32, NROI);
    reduce_bias_relu_kernel<<<2048, 256, 0, stream>>>(part, b1, fc6, NROI * DFC, DFC);

    // fc7 = relu(fc6 @ W2 + b2):  M=512 N=4096 K=4096, split-K=4
    gemm_bf16_kernel<<<512, 256, 0, stream>>>(fc6, W2T, part,
                                              DFC, DFC, DFC, DFC / 4, 4, 32, NROI);
    reduce_bias_relu_kernel<<<2048, 256, 0, stream>>>(part, b2, fc7, NROI * DFC, DFC);

    // head = fc7 @ [Wp|Ws]:  M=512 N=128(pad from 105) K=4096, split-K=16
    gemm_bf16_kernel<<<4 * KS_HEAD, 256, 0, stream>>>(fc7, WhT, part,
                                                      128, DFC, DFC, DFC / KS_HEAD,
                                                      4, 1, NROI);
    head_reduce_kernel<<<NROI, 128, 0, stream>>>(part, bp, bs, out);
}

// Round 3
// 465.624 us; speedup vs baseline: 1.5246x; 1.0402x over previous
//
#include <hip/hip_runtime.h>
#include <hip/hip_bf16.h>

using f32x4  = float          __attribute__((ext_vector_type(4)));
using bf16x8 = __bf16         __attribute__((ext_vector_type(8)));
using u16x8  = unsigned short __attribute__((ext_vector_type(8)));

#define C_CH 512
#define H_IN 37
#define W_IN 50
#define NPOS 1850       // 37*50
#define NROI 512
#define DIN  25088      // 512*49
#define DFC  4096
#define NPAR 84
#define NCLS 21
#define KS_HEAD 16

// prep mega-kernel block ranges
#define PB_X  232                 // transpose_x: 29*8
#define PB_WH 2048                // fill_whead: 128*4096/256
#define PB_W2 4096                // transpose_w2: 64*64
#define PB_W1 25088               // transpose_w1: 64*392
#define PB_TOT (PB_X + PB_WH + PB_W2 + PB_W1)   // 31464

__device__ __forceinline__ unsigned pack_bf16x2(float a, float b) {
    __hip_bfloat162 h;
    h.x = __float2bfloat16(a);
    h.y = __float2bfloat16(b);
    return *reinterpret_cast<unsigned*>(&h);
}

// ---------------------------------------------------------------------------
// W (K, 4096) fp32 -> WT (4096, Ktot) bf16 tile body.  perm=1 applies the
// RoI-k permutation: dest col k' = bin*512 + ch  from source row ch*49 + bin.
// ---------------------------------------------------------------------------
__device__ __forceinline__ void transpose_w_tile(
        const float* __restrict__ W, __hip_bfloat16* __restrict__ WT,
        int Ktot, int perm, int f0, int k0, int t, float (*tile)[65]) {
    int tc = t & 63, tr = t >> 6;
#pragma unroll
    for (int i = 0; i < 16; ++i) {
        int r  = tr + i * 4;            // k' offset
        int kp = k0 + r;
        int srow = perm ? ((kp & 511) * 49 + (kp >> 9)) : kp;
        tile[r][tc] = W[(size_t)srow * DFC + f0 + tc];
    }
    __syncthreads();
    int pairc = (t & 31) * 2;           // k' pair within tile
    int rw0   = t >> 5;                 // f within tile (0..7)
#pragma unroll
    for (int i = 0; i < 8; ++i) {
        int rw = rw0 + i * 8;
        unsigned pk = pack_bf16x2(tile[pairc][rw], tile[pairc + 1][rw]);
        *reinterpret_cast<unsigned*>(WT + (size_t)(f0 + rw) * Ktot + k0 + pairc) = pk;
    }
}

// ---------------------------------------------------------------------------
// Fused prep: transpose_x | fill_whead | transpose_w2 | transpose_w1.
// W1 blocks last so W1T writes are freshest in L3 when gemm1 starts.
// ---------------------------------------------------------------------------
__global__ __launch_bounds__(256) void prep_kernel(
        const float* __restrict__ x, float* __restrict__ xt,
        const float* __restrict__ W1, __hip_bfloat16* __restrict__ W1T,
        const float* __restrict__ W2, __hip_bfloat16* __restrict__ W2T,
        const float* __restrict__ Wp, const float* __restrict__ Ws,
        __hip_bfloat16* __restrict__ WhT) {
    __shared__ float tile[64][65];
    int b = blockIdx.x;
    int t = threadIdx.x;
    if (b < PB_X) {
        // x (512, 37, 50) fp32 -> xt (1850, 512) fp32
        int p0 = (b % 29) * 64;
        int c0 = (b / 29) * 64;
        int tc = t & 63, tr = t >> 6;
#pragma unroll
        for (int i = 0; i < 16; ++i) {
            int r = tr + i * 4;
            int p = p0 + tc;
            float v = 0.f;
            if (p < NPOS) v = x[(size_t)(c0 + r) * NPOS + p];
            tile[r][tc] = v;
        }
        __syncthreads();
#pragma unroll
        for (int i = 0; i < 16; ++i) {
            int rw = tr + i * 4;
            int p = p0 + rw;
            if (p < NPOS) xt[(size_t)p * C_CH + c0 + tc] = tile[tc][rw];
        }
    } else if (b < PB_X + PB_WH) {
        // Wp (4096,84) || Ws (4096,21) -> WhT[128][4096] bf16 zero-padded
        int idx = (b - PB_X) * 256 + t;
        int c = idx >> 12, k = idx & 4095;
        float v = 0.f;
        if (c < NPAR) v = Wp[(size_t)k * NPAR + c];
        else if (c < NPAR + NCLS) v = Ws[(size_t)k * NCLS + (c - NPAR)];
        WhT[idx] = __float2bfloat16(v);
    } else if (b < PB_X + PB_WH + PB_W2) {
        int r = b - (PB_X + PB_WH);
        transpose_w_tile(W2, W2T, DFC, 0, (r & 63) * 64, (r >> 6) * 64, t, tile);
    } else {
        int r = b - (PB_X + PB_WH + PB_W2);
        transpose_w_tile(W1, W1T, DIN, 1, (r & 63) * 64, (r >> 6) * 64, t, tile);
    }
}

// ---------------------------------------------------------------------------
// RoI max-pool.  One block (256 thr) per ROI; thread t owns channels 2t,2t+1.
// pooled layout: [n][bin*512 + ch] bf16 (K-permuted to match W1T).
// ---------------------------------------------------------------------------
__global__ __launch_bounds__(256) void roi_pool_kernel(
        const float* __restrict__ xt, const float* __restrict__ rois,
        __hip_bfloat16* __restrict__ pooled) {
    int n = blockIdx.x;
    int t = threadIdx.x;
    float4 rv = reinterpret_cast<const float4*>(rois)[n];
    int x1 = (int)fminf(fmaxf(rintf(rv.x * 0.0625f), 0.f), (float)W_IN);
    int y1 = (int)fminf(fmaxf(rintf(rv.y * 0.0625f), 0.f), (float)H_IN);
    int x2 = (int)fminf(fmaxf(rintf(rv.z * 0.0625f), 0.f), (float)W_IN);
    int y2 = (int)fminf(fmaxf(rintf(rv.w * 0.0625f), 0.f), (float)H_IN);
    bool valid = (x1 < x2) && (y1 < y2);
    unsigned* outp = reinterpret_cast<unsigned*>(pooled) + (size_t)n * (DIN / 2);
    if (!valid) {
        for (int b = 0; b < 49; ++b) outp[b * 256 + t] = 0u;
        return;
    }
    int x2e = min(x2, W_IN - 1), y2e = min(y2, H_IN - 1);
    int Hc = y2e - y1 + 1, Wc = x2e - x1 + 1;
    const float2* base = reinterpret_cast<const float2*>(xt);
    for (int i = 0; i < 7; ++i) {
        int rs = y1 + (i * Hc) / 7;
        int re = y1 + ((i + 1) * Hc + 6) / 7;
        for (int j = 0; j < 7; ++j) {
            int cs = x1 + (j * Wc) / 7;
            int ce = x1 + ((j + 1) * Wc + 6) / 7;
            float m0 = -__builtin_inff(), m1 = -__builtin_inff();
            for (int r = rs; r < re; ++r) {
                const float2* rowp = base + (size_t)r * (W_IN * C_CH / 2) + t;
                for (int c = cs; c < ce; ++c) {
                    float2 v = rowp[c * (C_CH / 2)];
                    m0 = fmaxf(m0, v.x);
                    m1 = fmaxf(m1, v.y);
                }
            }
            outp[(i * 7 + j) * 256 + t] = pack_bf16x2(m0, m1);
        }
    }
}

// ---------------------------------------------------------------------------
// bf16 GEMM, m97 structure: 128x128 tile, BK=64, 4 waves (2x2), 16x16x32 MFMA,
// global_load_lds width 16, XOR-swizzled LDS, split-K partials (fp32),
// XCD-chunked bijective blockIdx swizzle (gridDim.x must be a multiple of 8).
// A: [M][lda] bf16 row-major; Bt: [N][ldb] bf16 (B transposed, K contiguous).
// Cp: [KS][Mtot][N] fp32.
// ---------------------------------------------------------------------------
__device__ __forceinline__ void gload_lds16(const void* src, void* dst) {
    __builtin_amdgcn_global_load_lds(
        (const __attribute__((address_space(1))) void*)src,
        (__attribute__((address_space(3))) void*)dst, 16, 0, 0);
}

__global__ __launch_bounds__(256, 2) void gemm_bf16_kernel(
        const __hip_bfloat16* __restrict__ A,
        const __hip_bfloat16* __restrict__ Bt,
        float* __restrict__ Cp,
        int N, int lda, int ldb, int kChunk, int nMT, int nNT, int Mtot) {
    __shared__ __align__(16) char lA[128 * 128];
    __shared__ __align__(16) char lB[128 * 128];
    // XCD-chunked swizzle: physical XCD = blockIdx.x & 7 gets a contiguous
    // logical range, so the nMT blocks sharing a B-chunk co-reside on one XCD.
    int q = gridDim.x >> 3;
    int bid = (blockIdx.x & 7) * q + (blockIdx.x >> 3);
    int mt = bid % nMT;
    int nt = (bid / nMT) % nNT;
    int ks = bid / (nMT * nNT);
    int m0 = mt * 128, n0 = nt * 128;
    size_t k0 = (size_t)ks * kChunk;
    int t = threadIdx.x;
    int lane = t & 63, wid = t >> 6;

    const char* srcA[4]; const char* srcB[4];
    char* dstA[4]; char* dstB[4];
#pragma unroll
    for (int i = 0; i < 4; ++i) {
        int chunk = i * 4 + wid;                  // 1KB LDS chunk per wave-issue
        int p = chunk * 1024 + lane * 16;         // physical LDS byte
        int row = p >> 7;                         // 128B per row (64 bf16)
        int kb = (p & 127) ^ ((row & 7) << 4);    // inverse-swizzled source col
        srcA[i] = (const char*)A  + ((size_t)(m0 + row) * lda + k0) * 2 + kb;
        srcB[i] = (const char*)Bt + ((size_t)(n0 + row) * ldb + k0) * 2 + kb;
        dstA[i] = lA + chunk * 1024;
        dstB[i] = lB + chunk * 1024;
    }

    int wm = wid >> 1, wn = wid & 1;
    int swz = (lane & 7) << 4;
    int kb0 = (lane >> 4) << 4;                   // k-fragment byte offset
    int roA[4], roB[4];
#pragma unroll
    for (int f = 0; f < 4; ++f) {
        roA[f] = (wm * 64 + f * 16 + (lane & 15)) * 128;
        roB[f] = (wn * 64 + f * 16 + (lane & 15)) * 128;
    }

    f32x4 acc[4][4] = {};
    for (int kt = 0; kt < kChunk; kt += 64) {
#pragma unroll
        for (int i = 0; i < 4; ++i) gload_lds16(srcA[i], dstA[i]);
#pragma unroll
        for (int i = 0; i < 4; ++i) gload_lds16(srcB[i], dstB[i]);
#pragma unroll
        for (int i = 0; i < 4; ++i) { srcA[i] += 128; srcB[i] += 128; }
        __syncthreads();
#pragma unroll
        for (int ksub = 0; ksub < 2; ++ksub) {
            int kk = (kb0 | (ksub << 6)) ^ swz;
            bf16x8 af[4], bfr[4];
#pragma unroll
            for (int f = 0; f < 4; ++f)
                af[f] = *reinterpret_cast<const bf16x8*>(lA + roA[f] + kk);
#pragma unroll
            for (int f = 0; f < 4; ++f)
                bfr[f] = *reinterpret_cast<const bf16x8*>(lB + roB[f] + kk);
#pragma unroll
            for (int mf = 0; mf < 4; ++mf)
#pragma unroll
                for (int nf = 0; nf < 4; ++nf)
                    acc[mf][nf] = __builtin_amdgcn_mfma_f32_16x16x32_bf16(
                        af[mf], bfr[nf], acc[mf][nf], 0, 0, 0);
        }
        __syncthreads();
    }

    float* outp = Cp + (size_t)ks * Mtot * N;
    int rbase = m0 + wm * 64;
    int cbase = n0 + wn * 64 + (lane & 15);
    int rl = (lane >> 4) * 4;
#pragma unroll
    for (int mf = 0; mf < 4; ++mf)
#pragma unroll
        for (int nf = 0; nf < 4; ++nf)
#pragma unroll
            for (int r = 0; r < 4; ++r)
                outp[(size_t)(rbase + mf * 16 + rl + r) * N + cbase + nf * 16] =
                    acc[mf][nf][r];
}

// ---------------------------------------------------------------------------
// Sum KS=4 split-K partials + bias, ReLU, convert to bf16.
// ---------------------------------------------------------------------------
__global__ __launch_bounds__(256) void reduce_bias_relu_kernel(
        const float* __restrict__ P, const float* __restrict__ bias,
        __hip_bfloat16* __restrict__ out, int MN, int N) {
    int idx = blockIdx.x * blockDim.x + threadIdx.x;
    int e0 = idx * 4;
    if (e0 >= MN) return;
    f32x4 s = *reinterpret_cast<const f32x4*>(P + e0);
#pragma unroll
    for (int k = 1; k < 4; ++k)
        s += *reinterpret_cast<const f32x4*>(P + (size_t)k * MN + e0);
    f32x4 b = *reinterpret_cast<const f32x4*>(bias + (e0 & (N - 1)));
    s += b;
    uint2 pk;
    pk.x = pack_bf16x2(fmaxf(s[0], 0.f), fmaxf(s[1], 0.f));
    pk.y = pack_bf16x2(fmaxf(s[2], 0.f), fmaxf(s[3], 0.f));
    *reinterpret_cast<uint2*>(reinterpret_cast<char*>(out) + (size_t)e0 * 2) = pk;
}

// ---------------------------------------------------------------------------
// Sum KS_HEAD head partials + bias, scatter to (params, scores) output layout.
// P: [KS_HEAD][NROI][128] fp32.
// ---------------------------------------------------------------------------
__global__ __launch_bounds__(128) void head_reduce_kernel(
        const float* __restrict__ P, const float* __restrict__ bp,
        const float* __restrict__ bs, float* __restrict__ out) {
    int n = blockIdx.x, c = threadIdx.x;
    float s = 0.f;
#pragma unroll
    for (int ks = 0; ks < KS_HEAD; ++ks)
        s += P[(size_t)ks * NROI * 128 + (size_t)n * 128 + c];
    if (c < NPAR)
        out[(size_t)n * NPAR + c] = s + bp[c];
    else if (c < NPAR + NCLS)
        out[(size_t)NROI * NPAR + (size_t)n * NCLS + (c - NPAR)] = s + bs[c - NPAR];
}

// ---------------------------------------------------------------------------
extern "C" void kernel_launch(void* const* d_in, const int* in_sizes, int n_in,
                              void* d_out, int out_size, void* d_ws, size_t ws_size,
                              hipStream_t stream) {
    const float* x    = (const float*)d_in[0];
    const float* rois = (const float*)d_in[1];
    // d_in[2] roi_index: B=1 -> always 0, unused
    const float* W1 = (const float*)d_in[3];
    const float* b1 = (const float*)d_in[4];
    const float* W2 = (const float*)d_in[5];
    const float* b2 = (const float*)d_in[6];
    const float* Wp = (const float*)d_in[7];
    const float* bp = (const float*)d_in[8];
    const float* Ws = (const float*)d_in[9];
    const float* bs = (const float*)d_in[10];
    float* out = (float*)d_out;

    const size_t MB = 1ull << 20;
    char* ws = (char*)d_ws;
    float*          xt     = (float*)(ws + 0);                  // 3.62 MB
    __hip_bfloat16* pooled = (__hip_bfloat16*)(ws + 4   * MB);  // 24.5 MB
    __hip_bfloat16* WhT    = (__hip_bfloat16*)(ws + 30  * MB);  // 1 MB
    __hip_bfloat16* W1T    = (__hip_bfloat16*)(ws + 32  * MB);  // 196 MB
    __hip_bfloat16* W2T    = (__hip_bfloat16*)(ws + 240 * MB);  // 32 MB
    float*          part   = (float*)(ws + 274 * MB);           // 33.6 MB
    __hip_bfloat16* fc6    = (__hip_bfloat16*)(ws + 308 * MB);  // 4 MB
    __hip_bfloat16* fc7    = (__hip_bfloat16*)(ws + 313 * MB);  // 4 MB

    prep_kernel<<<PB_TOT, 256, 0, stream>>>(x, xt, W1, W1T, W2, W2T, Wp, Ws, WhT);
    roi_pool_kernel<<<NROI, 256, 0, stream>>>(xt, rois, pooled);

    // fc6 = relu(pooled @ W1 + b1):  M=512 N=4096 K=25088, split-K=4
    gemm_bf16_kernel<<<512, 256, 0, stream>>>(pooled, W1T, part,
                                              DFC, DIN, DIN, DIN / 4, 4, 32, NROI);
    reduce_bias_relu_kernel<<<2048, 256, 0, stream>>>(part, b1, fc6, NROI * DFC, DFC);

    // fc7 = relu(fc6 @ W2 + b2):  M=512 N=4096 K=4096, split-K=4
    gemm_bf16_kernel<<<512, 256, 0, stream>>>(fc6, W2T, part,
                                              DFC, DFC, DFC, DFC / 4, 4, 32, NROI);
    reduce_bias_relu_kernel<<<2048, 256, 0, stream>>>(part, b2, fc7, NROI * DFC, DFC);

    // head = fc7 @ [Wp|Ws]:  M=512 N=128(pad from 105) K=4096, split-K=16
    gemm_bf16_kernel<<<4 * KS_HEAD, 256, 0, stream>>>(fc7, WhT, part,
                                                      128, DFC, DFC, DFC / KS_HEAD,
                                                      4, 1, NROI);
    head_reduce_kernel<<<NROI, 128, 0, stream>>>(part, bp, bs, out);
}

// Round 4
// 410.473 us; speedup vs baseline: 1.7294x; 1.1344x over previous
//
#include <hip/hip_runtime.h>
#include <hip/hip_bf16.h>

using f32x4  = float          __attribute__((ext_vector_type(4)));
using bf16x8 = __bf16         __attribute__((ext_vector_type(8)));
using u16x8  = unsigned short __attribute__((ext_vector_type(8)));

#define C_CH 512
#define H_IN 37
#define W_IN 50
#define NPOS 1850       // 37*50
#define NROI 512
#define DIN  25088      // 512*49
#define DFC  4096
#define NPAR 84
#define NCLS 21
#define KS_HEAD 16

// prep mega-kernel block ranges
#define PB_X  232                 // transpose_x: 29*8
#define PB_WH 2048                // fill_whead: 4096*128/256
#define PB_TOT (PB_X + PB_WH)     // 2280

__device__ __forceinline__ unsigned pack_bf16x2(float a, float b) {
    __hip_bfloat162 h;
    h.x = __float2bfloat16(a);
    h.y = __float2bfloat16(b);
    return *reinterpret_cast<unsigned*>(&h);
}

// ---------------------------------------------------------------------------
// Fused prep: transpose_x | fill Whp (fp32 [4096][128], Wp||Ws zero-padded).
// ---------------------------------------------------------------------------
__global__ __launch_bounds__(256) void prep_kernel(
        const float* __restrict__ x, float* __restrict__ xt,
        const float* __restrict__ Wp, const float* __restrict__ Ws,
        float* __restrict__ Whp) {
    __shared__ float tile[64][65];
    int b = blockIdx.x;
    int t = threadIdx.x;
    if (b < PB_X) {
        // x (512, 37, 50) fp32 -> xt (1850, 512) fp32
        int p0 = (b % 29) * 64;
        int c0 = (b / 29) * 64;
        int tc = t & 63, tr = t >> 6;
#pragma unroll
        for (int i = 0; i < 16; ++i) {
            int r = tr + i * 4;
            int p = p0 + tc;
            float v = 0.f;
            if (p < NPOS) v = x[(size_t)(c0 + r) * NPOS + p];
            tile[r][tc] = v;
        }
        __syncthreads();
#pragma unroll
        for (int i = 0; i < 16; ++i) {
            int rw = tr + i * 4;
            int p = p0 + rw;
            if (p < NPOS) xt[(size_t)p * C_CH + c0 + tc] = tile[tc][rw];
        }
    } else {
        // Whp[k][c] fp32: c<84 -> Wp[k][c]; c<105 -> Ws[k][c-84]; else 0
        int idx = (b - PB_X) * 256 + t;
        int k = idx >> 7, c = idx & 127;
        float v = 0.f;
        if (c < NPAR) v = Wp[(size_t)k * NPAR + c];
        else if (c < NPAR + NCLS) v = Ws[(size_t)k * NCLS + (c - NPAR)];
        Whp[idx] = v;
    }
}

// ---------------------------------------------------------------------------
// RoI max-pool.  One block (256 thr) per ROI; thread t owns channels 2t,2t+1.
// pooled layout: [n][bin*512 + ch] bf16 (K-permuted; gemm1 permutes W1 rows).
// ---------------------------------------------------------------------------
__global__ __launch_bounds__(256) void roi_pool_kernel(
        const float* __restrict__ xt, const float* __restrict__ rois,
        __hip_bfloat16* __restrict__ pooled) {
    int n = blockIdx.x;
    int t = threadIdx.x;
    float4 rv = reinterpret_cast<const float4*>(rois)[n];
    int x1 = (int)fminf(fmaxf(rintf(rv.x * 0.0625f), 0.f), (float)W_IN);
    int y1 = (int)fminf(fmaxf(rintf(rv.y * 0.0625f), 0.f), (float)H_IN);
    int x2 = (int)fminf(fmaxf(rintf(rv.z * 0.0625f), 0.f), (float)W_IN);
    int y2 = (int)fminf(fmaxf(rintf(rv.w * 0.0625f), 0.f), (float)H_IN);
    bool valid = (x1 < x2) && (y1 < y2);
    unsigned* outp = reinterpret_cast<unsigned*>(pooled) + (size_t)n * (DIN / 2);
    if (!valid) {
        for (int b = 0; b < 49; ++b) outp[b * 256 + t] = 0u;
        return;
    }
    int x2e = min(x2, W_IN - 1), y2e = min(y2, H_IN - 1);
    int Hc = y2e - y1 + 1, Wc = x2e - x1 + 1;
    const float2* base = reinterpret_cast<const float2*>(xt);
    for (int i = 0; i < 7; ++i) {
        int rs = y1 + (i * Hc) / 7;
        int re = y1 + ((i + 1) * Hc + 6) / 7;
        for (int j = 0; j < 7; ++j) {
            int cs = x1 + (j * Wc) / 7;
            int ce = x1 + ((j + 1) * Wc + 6) / 7;
            float m0 = -__builtin_inff(), m1 = -__builtin_inff();
            for (int r = rs; r < re; ++r) {
                const float2* rowp = base + (size_t)r * (W_IN * C_CH / 2) + t;
                for (int c = cs; c < ce; ++c) {
                    float2 v = rowp[c * (C_CH / 2)];
                    m0 = fmaxf(m0, v.x);
                    m1 = fmaxf(m1, v.y);
                }
            }
            outp[(i * 7 + j) * 256 + t] = pack_bf16x2(m0, m1);
        }
    }
}

// ---------------------------------------------------------------------------
// bf16-A x fp32-B GEMM.  128x128 tile, BK=64, 4 waves (2x2), 16x16x32 MFMA.
// A: bf16 [M][lda], staged via global_load_lds (pre-swizzled source).
// B: fp32 [K][ldbn] (N contiguous!), reg-staged: 8x float4 per thread per
//    K-step (thread owns 8k x 4n), cvt_pk -> 4x ds_write_b128 into [n][k] LDS.
// LDS XOR swizzle: slot ^= ((row ^ (row>>3)) & 7)  (16B slots) -- spreads both
// the B-writer rows (4L+j) and the fragment-reader rows (f*16+lane&15).
// perm=1: B row k' = bin*512+ch maps to source row ch*49+bin (RoI-k permute).
// Cp: [KS][Mtot][N] fp32 split-K partials.  XCD-chunked block swizzle.
// ---------------------------------------------------------------------------
__device__ __forceinline__ void gload_lds16(const void* src, void* dst) {
    __builtin_amdgcn_global_load_lds(
        (const __attribute__((address_space(1))) void*)src,
        (__attribute__((address_space(3))) void*)dst, 16, 0, 0);
}

__global__ __launch_bounds__(256, 2) void gemm_f32b_kernel(
        const __hip_bfloat16* __restrict__ A,
        const float* __restrict__ Bf,
        float* __restrict__ Cp,
        int N, int lda, int ldbn, int kChunk, int nMT, int nNT, int Mtot,
        int perm) {
    __shared__ __align__(16) char lA[128 * 128];
    __shared__ __align__(16) char lB[128 * 128];
    int q = gridDim.x >> 3;
    int bid = (blockIdx.x & 7) * q + (blockIdx.x >> 3);
    int mt = bid % nMT;
    int nt = (bid / nMT) % nNT;
    int ks = bid / (nMT * nNT);
    int m0 = mt * 128, n0 = nt * 128;
    int k0 = ks * kChunk;
    int t = threadIdx.x;
    int lane = t & 63, wid = t >> 6;

    // A staging: pre-swizzled global source, linear LDS dest
    const char* srcA[4]; char* dstA[4];
#pragma unroll
    for (int i = 0; i < 4; ++i) {
        int chunk = i * 4 + wid;
        int p = chunk * 1024 + lane * 16;
        int row = p >> 7;
        int swz = ((row ^ (row >> 3)) & 7) << 4;
        srcA[i] = (const char*)A + ((size_t)(m0 + row) * lda + k0) * 2
                  + ((p & 127) ^ swz);
        dstA[i] = lA + chunk * 1024;
    }

    // B staging mapping: thread owns (n4..n4+3) x (k8..k8+7)
    int n4 = (t & 31) * 4;
    int k8 = (t >> 5) * 8;
    int woff[4];
#pragma unroll
    for (int j = 0; j < 4; ++j) {
        int row = n4 + j;
        int swz = ((row ^ (row >> 3)) & 7) << 4;
        woff[j] = row * 128 + ((k8 * 2) ^ swz);
    }

    // fragment read offsets
    int wm = wid >> 1, wn = wid & 1;
    int kb0 = (lane >> 4) << 4;
    int roA[4], roB[4], sA[4], sB[4];
#pragma unroll
    for (int f = 0; f < 4; ++f) {
        int ra = wm * 64 + f * 16 + (lane & 15);
        int rb = wn * 64 + f * 16 + (lane & 15);
        roA[f] = ra * 128; sA[f] = ((ra ^ (ra >> 3)) & 7) << 4;
        roB[f] = rb * 128; sB[f] = ((rb ^ (rb >> 3)) & 7) << 4;
    }

    int nkt = kChunk >> 6;
    f32x4 acc[4][4] = {};
    f32x4 v[8];

    // prologue: B loads for tile 0
    {
        int kb = k0;
        int rbase = perm ? ((kb & 511) * 49 + (kb >> 9)) : kb;
        int rstr  = perm ? 49 : 1;
#pragma unroll
        for (int p = 0; p < 8; ++p)
            v[p] = *reinterpret_cast<const f32x4*>(
                Bf + (size_t)(rbase + (k8 + p) * rstr) * ldbn + n0 + n4);
    }

    for (int kt = 0; kt < nkt; ++kt) {
#pragma unroll
        for (int i = 0; i < 4; ++i) { gload_lds16(srcA[i], dstA[i]); srcA[i] += 128; }
        // cvt + transposed LDS write of B tile kt (waits the in-flight loads)
#pragma unroll
        for (int j = 0; j < 4; ++j) {
            uint4 w;
            w.x = pack_bf16x2(v[0][j], v[1][j]);
            w.y = pack_bf16x2(v[2][j], v[3][j]);
            w.z = pack_bf16x2(v[4][j], v[5][j]);
            w.w = pack_bf16x2(v[6][j], v[7][j]);
            *reinterpret_cast<uint4*>(lB + woff[j]) = w;
        }
        __syncthreads();
        // issue B loads for tile kt+1; they fly under the MFMA below
        if (kt + 1 < nkt) {
            int kb = k0 + (kt + 1) * 64;
            int rbase = perm ? ((kb & 511) * 49 + (kb >> 9)) : kb;
            int rstr  = perm ? 49 : 1;
#pragma unroll
            for (int p = 0; p < 8; ++p)
                v[p] = *reinterpret_cast<const f32x4*>(
                    Bf + (size_t)(rbase + (k8 + p) * rstr) * ldbn + n0 + n4);
        }
#pragma unroll
        for (int ksub = 0; ksub < 2; ++ksub) {
            int kk = kb0 | (ksub << 6);
            bf16x8 af[4], bfr[4];
#pragma unroll
            for (int f = 0; f < 4; ++f)
                af[f] = *reinterpret_cast<const bf16x8*>(lA + roA[f] + (kk ^ sA[f]));
#pragma unroll
            for (int f = 0; f < 4; ++f)
                bfr[f] = *reinterpret_cast<const bf16x8*>(lB + roB[f] + (kk ^ sB[f]));
#pragma unroll
            for (int mf = 0; mf < 4; ++mf)
#pragma unroll
                for (int nf = 0; nf < 4; ++nf)
                    acc[mf][nf] = __builtin_amdgcn_mfma_f32_16x16x32_bf16(
                        af[mf], bfr[nf], acc[mf][nf], 0, 0, 0);
        }
        __syncthreads();
    }

    float* outp = Cp + (size_t)ks * Mtot * N;
    int rbase = m0 + wm * 64;
    int cbase = n0 + wn * 64 + (lane & 15);
    int rl = (lane >> 4) * 4;
#pragma unroll
    for (int mf = 0; mf < 4; ++mf)
#pragma unroll
        for (int nf = 0; nf < 4; ++nf)
#pragma unroll
            for (int r = 0; r < 4; ++r)
                outp[(size_t)(rbase + mf * 16 + rl + r) * N + cbase + nf * 16] =
                    acc[mf][nf][r];
}

// ---------------------------------------------------------------------------
// Sum KS=4 split-K partials + bias, ReLU, convert to bf16.
// ---------------------------------------------------------------------------
__global__ __launch_bounds__(256) void reduce_bias_relu_kernel(
        const float* __restrict__ P, const float* __restrict__ bias,
        __hip_bfloat16* __restrict__ out, int MN, int N) {
    int idx = blockIdx.x * blockDim.x + threadIdx.x;
    int e0 = idx * 4;
    if (e0 >= MN) return;
    f32x4 s = *reinterpret_cast<const f32x4*>(P + e0);
#pragma unroll
    for (int k = 1; k < 4; ++k)
        s += *reinterpret_cast<const f32x4*>(P + (size_t)k * MN + e0);
    f32x4 b = *reinterpret_cast<const f32x4*>(bias + (e0 & (N - 1)));
    s += b;
    uint2 pk;
    pk.x = pack_bf16x2(fmaxf(s[0], 0.f), fmaxf(s[1], 0.f));
    pk.y = pack_bf16x2(fmaxf(s[2], 0.f), fmaxf(s[3], 0.f));
    *reinterpret_cast<uint2*>(reinterpret_cast<char*>(out) + (size_t)e0 * 2) = pk;
}

// ---------------------------------------------------------------------------
// Sum KS_HEAD head partials + bias, scatter to (params, scores) output layout.
// P: [KS_HEAD][NROI][128] fp32.
// ---------------------------------------------------------------------------
__global__ __launch_bounds__(128) void head_reduce_kernel(
        const float* __restrict__ P, const float* __restrict__ bp,
        const float* __restrict__ bs, float* __restrict__ out) {
    int n = blockIdx.x, c = threadIdx.x;
    float s = 0.f;
#pragma unroll
    for (int ks = 0; ks < KS_HEAD; ++ks)
        s += P[(size_t)ks * NROI * 128 + (size_t)n * 128 + c];
    if (c < NPAR)
        out[(size_t)n * NPAR + c] = s + bp[c];
    else if (c < NPAR + NCLS)
        out[(size_t)NROI * NPAR + (size_t)n * NCLS + (c - NPAR)] = s + bs[c - NPAR];
}

// ---------------------------------------------------------------------------
extern "C" void kernel_launch(void* const* d_in, const int* in_sizes, int n_in,
                              void* d_out, int out_size, void* d_ws, size_t ws_size,
                              hipStream_t stream) {
    const float* x    = (const float*)d_in[0];
    const float* rois = (const float*)d_in[1];
    // d_in[2] roi_index: B=1 -> always 0, unused
    const float* W1 = (const float*)d_in[3];
    const float* b1 = (const float*)d_in[4];
    const float* W2 = (const float*)d_in[5];
    const float* b2 = (const float*)d_in[6];
    const float* Wp = (const float*)d_in[7];
    const float* bp = (const float*)d_in[8];
    const float* Ws = (const float*)d_in[9];
    const float* bs = (const float*)d_in[10];
    float* out = (float*)d_out;

    const size_t MB = 1ull << 20;
    char* ws = (char*)d_ws;
    float*          xt     = (float*)(ws + 0);                  // 3.62 MB
    __hip_bfloat16* pooled = (__hip_bfloat16*)(ws + 4   * MB);  // 24.5 MB
    float*          Whp    = (float*)(ws + 30  * MB);           // 2 MB
    float*          part   = (float*)(ws + 34  * MB);           // 33.6 MB
    __hip_bfloat16* fc6    = (__hip_bfloat16*)(ws + 70  * MB);  // 4 MB
    __hip_bfloat16* fc7    = (__hip_bfloat16*)(ws + 75  * MB);  // 4 MB

    prep_kernel<<<PB_TOT, 256, 0, stream>>>(x, xt, Wp, Ws, Whp);
    roi_pool_kernel<<<NROI, 256, 0, stream>>>(xt, rois, pooled);

    // fc6 = relu(pooled @ W1 + b1):  M=512 N=4096 K=25088, split-K=4, perm
    gemm_f32b_kernel<<<512, 256, 0, stream>>>(pooled, W1, part,
                                              DFC, DIN, DFC, DIN / 4, 4, 32, NROI, 1);
    reduce_bias_relu_kernel<<<2048, 256, 0, stream>>>(part, b1, fc6, NROI * DFC, DFC);

    // fc7 = relu(fc6 @ W2 + b2):  M=512 N=4096 K=4096, split-K=4
    gemm_f32b_kernel<<<512, 256, 0, stream>>>(fc6, W2, part,
                                              DFC, DFC, DFC, DFC / 4, 4, 32, NROI, 0);
    reduce_bias_relu_kernel<<<2048, 256, 0, stream>>>(part, b2, fc7, NROI * DFC, DFC);

    // head = fc7 @ [Wp|Ws]:  M=512 N=128(pad from 105) K=4096, split-K=16
    gemm_f32b_kernel<<<4 * KS_HEAD, 256, 0, stream>>>(fc7, Whp, part,
                                                      128, DFC, 128, DFC / KS_HEAD,
                                                      4, 1, NROI, 0);
    head_reduce_kernel<<<NROI, 128, 0, stream>>>(part, bp, bs, out);
}